// Round 14
// baseline (408.184 us; speedup 1.0000x reference)
//
#include <hip/hip_runtime.h>

#define B_DIM 128
#define T_DIM 512
#define C_DIM 384
#define NH_DIM 6
#define HD_DIM 64
#define QKV_LD 1152  // 3*C

typedef __bf16 bf16x8 __attribute__((ext_vector_type(8)));
typedef __bf16 bf16x4 __attribute__((ext_vector_type(4)));
typedef float f32x4 __attribute__((ext_vector_type(4)));

// (1/sqrt(64)) * log2(e): folded into Q inside gemm1's epilogue, so attention
// scores come out of QK^T already in the exp2 domain.
#define K_SCALE 0.18033688011112042f

// direct global->LDS DMA, 16B per lane. LDS dest is wave-uniform base +
// lane*16 (m104); the global source is per-lane, which is how the k-slot
// swizzle is applied (m173 pattern).
__device__ __forceinline__ void gload_lds16(const __bf16* g, __bf16* l) {
  __builtin_amdgcn_global_load_lds(
      (const __attribute__((address_space(1))) void*)g,
      (__attribute__((address_space(3))) void*)l, 16, 0, 0);
}

// ---------------- fused fp32 -> bf16 cast for x, Wqkv, Wout ----------------
#define X_F4 6291456
#define WQKV_F4 110592
#define WOUT_F4 36864
__global__ __launch_bounds__(256) void cast_all(const float* __restrict__ x,
                                                const float* __restrict__ wqkv,
                                                const float* __restrict__ wout,
                                                __bf16* __restrict__ xb,
                                                __bf16* __restrict__ wqkvb,
                                                __bf16* __restrict__ woutb) {
  int i = blockIdx.x * blockDim.x + threadIdx.x;
  const float4* src;
  bf16x4* dst;
  if (i < X_F4) {
    src = (const float4*)x + i;
    dst = (bf16x4*)xb + i;
  } else if (i < X_F4 + WQKV_F4) {
    src = (const float4*)wqkv + (i - X_F4);
    dst = (bf16x4*)wqkvb + (i - X_F4);
  } else {
    src = (const float4*)wout + (i - X_F4 - WQKV_F4);
    dst = (bf16x4*)woutb + (i - X_F4 - WQKV_F4);
  }
  float4 v = *src;
  bf16x4 o;
  o[0] = (__bf16)v.x; o[1] = (__bf16)v.y; o[2] = (__bf16)v.z; o[3] = (__bf16)v.w;
  *dst = o;
}

// ---------------- C = A * B^T  (swapped-D epilogue, split q/k/v^T) ----------
// A[M][K] bf16 (DMA-staged), B[N][K] bf16. MFMA computed as mfma(bf, af) ->
// D is C^T-fragmented: LANE dim (lr) = C-row m, REGISTER dim (quad*4+r) =
// C-col n. Each thread's 4 regs are 4 CONSECUTIVE output columns:
//  * gemm2 (Cf): one f32x4 16B store per (i,j)  (was 64 scalar 4B stores)
//  * q/k: one bf16x4 8B store per (i,j); rope pair (d,d+8) = quad^2 ->
//    shfl_xor(v,32); cos/sin index (quad&1)*4+r  (was 64 scalar 2B stores)
//  * v: direct vt[d][t] scalar stores -- t is now the lane dim so each
//    (i,j,r) instr writes 4 d-rows x 32B contiguous; the R13 in-LDS
//    transpose pass + its 2 barriers are DELETED.
// T1 XCD swizzle (R11/R12-verified: FETCH 216 -> 32 MB). Staging:
// global_load_lds width=16, LINEAR [128][32] tiles, both-sides XOR k-slot
// swizzle keyed on (row>>1)&3 -> 2-way alias = free (m136).
__global__ __launch_bounds__(256) void gemm_bt(const __bf16* __restrict__ A,
                                               const __bf16* __restrict__ Bm,
                                               __bf16* __restrict__ Cbq,
                                               __bf16* __restrict__ Cbk,
                                               __bf16* __restrict__ vt,
                                               float* __restrict__ Cf,
                                               const float* __restrict__ cosp,
                                               const float* __restrict__ sinp,
                                               int M, int N, int K) {
  __shared__ __attribute__((aligned(16))) __bf16 As[128 * 32];  // 8 KB
  __shared__ __attribute__((aligned(16))) __bf16 Bs[128 * 32];  // 8 KB
  const int nwg = gridDim.x * gridDim.y;
  const int bid = blockIdx.x + gridDim.x * blockIdx.y;  // dispatch order (x fastest)
  const int per = nwg >> 3;
  const int swz = (bid & 7) * per + (bid >> 3);         // T1, bijective (nwg%8==0)
  const int m0 = (swz / gridDim.x) * 128;
  const int n0 = (swz % gridDim.x) * 128;
  const int tid = threadIdx.x;
  const int wave = tid >> 6;
  const int lane = tid & 63;
  const int lr = lane & 15;
  const int quad = lane >> 4;
  const int wm = (wave & 1) * 64;
  const int wn = (wave >> 1) * 64;
  const int ca0 = wave * 2, ca1 = wave * 2 + 1;
  const int srow = lane >> 2;
  const int row0 = ca0 * 16 + srow, row1 = ca1 * 16 + srow;
  const int slot = (lane & 3) ^ ((lane >> 3) & 3);  // (l&3) ^ ((srow>>1)&3)
  const int rs = (quad ^ ((lr >> 1) & 3)) * 8;
  // hoisted staging pointers (advance 32 elems per K-step)
  const __bf16* pA0 = &A[(size_t)(m0 + row0) * K + slot * 8];
  const __bf16* pA1 = &A[(size_t)(m0 + row1) * K + slot * 8];
  const __bf16* pB0 = &Bm[(size_t)(n0 + row0) * K + slot * 8];
  const __bf16* pB1 = &Bm[(size_t)(n0 + row1) * K + slot * 8];
  f32x4 acc[4][4] = {};
  for (int k0 = 0; k0 < K; k0 += 32) {
    __syncthreads();  // prev iteration's LDS reads done
    gload_lds16(pA0, &As[ca0 * 512]);
    gload_lds16(pA1, &As[ca1 * 512]);
    gload_lds16(pB0, &Bs[ca0 * 512]);
    gload_lds16(pB1, &Bs[ca1 * 512]);
    pA0 += 32; pA1 += 32; pB0 += 32; pB1 += 32;
    __syncthreads();  // compiler drains vmcnt before the barrier
    bf16x8 af[4], bf[4];
#pragma unroll
    for (int i = 0; i < 4; ++i)
      af[i] = *(bf16x8*)&As[(wm + i * 16 + lr) * 32 + rs];
#pragma unroll
    for (int j = 0; j < 4; ++j)
      bf[j] = *(bf16x8*)&Bs[(wn + j * 16 + lr) * 32 + rs];
#pragma unroll
    for (int i = 0; i < 4; ++i)
#pragma unroll
      for (int j = 0; j < 4; ++j)
        acc[i][j] = __builtin_amdgcn_mfma_f32_16x16x32_bf16(bf[j], af[i], acc[i][j], 0, 0, 0);
  }
  // Swapped D: row m = (i, lr), col n = (j, quad*4 + r)
  if (Cf) {  // generic fp32 path (gemm2): 16B vector stores
#pragma unroll
    for (int i = 0; i < 4; ++i) {
      const int gm = m0 + wm + i * 16 + lr;
#pragma unroll
      for (int j = 0; j < 4; ++j) {
        const int gn = n0 + wn + j * 16 + quad * 4;
        *(f32x4*)&Cf[(size_t)gm * N + gn] = acc[i][j];
      }
    }
    return;
  }
  if (n0 >= 2 * C_DIM) {
    // ---- V block: direct vt[(b*6+h)*64+d][t] stores (t = lane dim) ----
    const int tb = (m0 & (T_DIM - 1)) + wm;
    const int bb = m0 >> 9;                     // m0 / T_DIM
    const int dcb = n0 - 2 * C_DIM + wn;        // multiple of 64
#pragma unroll
    for (int i = 0; i < 4; ++i) {
      const int t = tb + i * 16 + lr;
#pragma unroll
      for (int j = 0; j < 4; ++j) {
#pragma unroll
        for (int r = 0; r < 4; ++r) {
          const int dfull = dcb + j * 16 + quad * 4 + r;
          const int hh = dfull >> 6, dd = dfull & 63;
          vt[((size_t)(bb * NH_DIM + hh) * 64 + dd) * T_DIM + t] = (__bf16)acc[i][j][r];
        }
      }
    }
    return;
  }
  // ---- q / k block: packed [M][384], bf16x4 stores (+rope, +K_SCALE) ----
  const bool isQ = (n0 < C_DIM);
  __bf16* dst = isQ ? Cbq : Cbk;
  const int colb0 = n0 - (isQ ? 0 : C_DIM);
  const float qs = isQ ? K_SCALE : 1.0f;
#pragma unroll
  for (int i = 0; i < 4; ++i) {
    const int gm = m0 + wm + i * 16 + lr;
    const int t = gm & (T_DIM - 1);
#pragma unroll
    for (int j = 0; j < 4; ++j) {
      const int cb = colb0 + wn + j * 16;
      bf16x4 w;
      if ((cb & 63) == 0) {  // rope block: d_local = quad*4+r in [0,16)
#pragma unroll
        for (int r = 0; r < 4; ++r) {
          float v = acc[i][j][r];
          float p = __shfl_xor(v, 32, 64);  // partner d <-> d+8 = quad^2
          float c = cosp[t * 8 + (quad & 1) * 4 + r];
          float s = sinp[t * 8 + (quad & 1) * 4 + r];
          v = (quad & 2) ? __builtin_fmaf(v, c, p * s)
                         : __builtin_fmaf(v, c, -p * s);
          w[r] = (__bf16)(v * qs);
        }
      } else {
#pragma unroll
        for (int r = 0; r < 4; ++r) w[r] = (__bf16)(acc[i][j][r] * qs);
      }
      *(bf16x4*)&dst[(size_t)gm * C_DIM + cb + quad * 4] = w;
    }
  }
}

// ------- causal flash attention: paired q-tiles, no-max softmax, MFMA rowsum -
// (R9 structure + T1 swizzle.) This round: PV and rowsum MFMAs swapped ->
// oa reg dim = d (4 consecutive), lane dim = q-row; l lands in the LANE
// domain directly (every reg of lacc equals l[q=lr]). O-write: 8 bf16x4
// stores per thread (was 32 scalar), divide uses lane-local 1/l, no shfl.
__global__ __launch_bounds__(256) void attn_kernel(const __bf16* __restrict__ qb,
                                                   const __bf16* __restrict__ kb,
                                                   const __bf16* __restrict__ vt,
                                                   __bf16* __restrict__ o) {
  __shared__ __attribute__((aligned(16))) __bf16 K0s[64 * 64];   // 8 KB each
  __shared__ __attribute__((aligned(16))) __bf16 K1s[64 * 64];
  __shared__ __attribute__((aligned(16))) __bf16 V0s[64 * 64];
  __shared__ __attribute__((aligned(16))) __bf16 V1s[64 * 64];
  // T1: 3072 blocks, 8 XCDs -> chunks of 384
  const int bid = blockIdx.x;
  const int swz = (bid & 7) * 384 + (bid >> 3);
  const int pair = swz & 3;                 // 0..3
  const int h = (swz >> 2) % NH_DIM;
  const int b = swz / (4 * NH_DIM);
  const int qlo = pair, qhi = 7 - pair;
  const int tid = threadIdx.x;
  const int wave = tid >> 6;
  const int lane = tid & 63;
  const int lr = lane & 15;
  const int quad = lane >> 4;
  const __bf16* qbase = qb + (size_t)b * T_DIM * C_DIM + h * HD_DIM;
  const __bf16* kbase = kb + (size_t)b * T_DIM * C_DIM + h * HD_DIM;
  const __bf16* vtb = vt + (size_t)(b * NH_DIM + h) * HD_DIM * T_DIM;  // [d][t]
  const int qrow_lo = qlo * 64 + wave * 16;
  const int qrow_hi = qhi * 64 + wave * 16;
  // Q fragments, both strips: [idx=lane&15][k=quad*8+j]
  bf16x8 qfl[2], qfh[2];
#pragma unroll
  for (int ks = 0; ks < 2; ++ks) {
    qfl[ks] = *(const bf16x8*)&qbase[(size_t)(qrow_lo + lr) * C_DIM + ks * 32 + quad * 8];
    qfh[ks] = *(const bf16x8*)&qbase[(size_t)(qrow_hi + lr) * C_DIM + ks * 32 + quad * 8];
  }
  f32x4 oaL[4] = {}, oaH[4] = {};
  f32x4 lL = {}, lH = {};
  bf16x8 vones;
#pragma unroll
  for (int e = 0; e < 8; ++e) vones[e] = (__bf16)1.0f;
  const int skey = (((lane >> 3) & 3) << 1) | (wave & 1);
  const int gsl = ((lane & 7) ^ skey) * 8;  // global col (elements)
  const int grA = wave * 8 + (lane >> 3);
  const int grB = grA + 32;
  const int ldsA = wave * 512;        // elements
  const int ldsB = (wave + 4) * 512;
  auto stage = [&](int kt, __bf16* KT, __bf16* VT) {
    const __bf16* ks = kbase + (size_t)(kt * 64) * C_DIM;
    const __bf16* vs = vtb + kt * 64;
    gload_lds16(&ks[(size_t)grA * C_DIM + gsl], KT + ldsA);
    gload_lds16(&ks[(size_t)grB * C_DIM + gsl], KT + ldsB);
    gload_lds16(&vs[(size_t)grA * T_DIM + gsl], VT + ldsA);
    gload_lds16(&vs[(size_t)grB * T_DIM + gsl], VT + ldsB);
  };
  const int keyK = ((lr & 3) << 1) | ((lr >> 2) & 1);
  const int keyV = ((lr & 3) << 1) | ((lr >> 3) & 1);
  const int swK0 = (quad ^ keyK) * 8, swK1 = ((4 + quad) ^ keyK) * 8;
  const int swV0 = (quad ^ keyV) * 8, swV1 = ((4 + quad) ^ keyV) * 8;
  const int rkbase = ((lr >> 2) & 3) * 8 + (lr & 3);  // sigma row base for this lane
  auto body = [&](const __bf16* KT, const __bf16* VT, const bf16x8 (&qf)[2],
                  f32x4 (&oa)[4], f32x4& lacc, int myq, bool diag, int kt) {
    f32x4 sj[4];
#pragma unroll
    for (int j = 0; j < 4; ++j) {
      const int rK = (j >> 1) * 32 + (j & 1) * 4 + rkbase;
      bf16x8 kf0 = *(const bf16x8*)&KT[rK * 64 + swK0];
      bf16x8 kf1 = *(const bf16x8*)&KT[rK * 64 + swK1];
      f32x4 z = {};
      z = __builtin_amdgcn_mfma_f32_16x16x32_bf16(kf0, qf[0], z, 0, 0, 0);
      z = __builtin_amdgcn_mfma_f32_16x16x32_bf16(kf1, qf[1], z, 0, 0, 0);
      sj[j] = z;
    }
    if (diag) {
#pragma unroll
      for (int j = 0; j < 4; ++j)
#pragma unroll
        for (int r = 0; r < 4; ++r) {
          int key = kt * 64 + (j >> 1) * 32 + quad * 8 + (j & 1) * 4 + r;
          if (key > myq) sj[j][r] = -3.0e38f;  // exp2 -> 0
        }
    }
    bf16x8 pf0, pf1;
#pragma unroll
    for (int j = 0; j < 4; ++j)
#pragma unroll
      for (int r = 0; r < 4; ++r) {
        float pv = exp2f(sj[j][r]);
        const int jj = (j & 1) * 4 + r;
        if (j < 2) pf0[jj] = (__bf16)pv; else pf1[jj] = (__bf16)pv;
      }
    // swapped PV: oa reg dim = d, lane = q-row; rowsum -> lane-domain l
#pragma unroll
    for (int dt = 0; dt < 4; ++dt) {
      bf16x8 vf0 = *(const bf16x8*)&VT[(dt * 16 + lr) * 64 + swV0];
      bf16x8 vf1 = *(const bf16x8*)&VT[(dt * 16 + lr) * 64 + swV1];
      oa[dt] = __builtin_amdgcn_mfma_f32_16x16x32_bf16(vf0, pf0, oa[dt], 0, 0, 0);
      oa[dt] = __builtin_amdgcn_mfma_f32_16x16x32_bf16(vf1, pf1, oa[dt], 0, 0, 0);
    }
    lacc = __builtin_amdgcn_mfma_f32_16x16x32_bf16(vones, pf0, lacc, 0, 0, 0);
    lacc = __builtin_amdgcn_mfma_f32_16x16x32_bf16(vones, pf1, lacc, 0, 0, 0);
  };
  // prologue
  stage(0, K0s, V0s);
  __syncthreads();  // drains DMA -> tile 0 ready
  int kt = 0;
  while (true) {
    if (kt < qhi) stage(kt + 1, K1s, V1s);
    if (kt <= qlo) body(K0s, V0s, qfl, oaL, lL, qrow_lo + lr, kt == qlo, kt);
    body(K0s, V0s, qfh, oaH, lH, qrow_hi + lr, kt == qhi, kt);
    __syncthreads();  // drains kt+1 DMA; guards buf0 reuse
    ++kt;
    if (kt > qhi) break;
    if (kt < qhi) stage(kt + 1, K0s, V0s);
    if (kt <= qlo) body(K1s, V1s, qfl, oaL, lL, qrow_lo + lr, kt == qlo, kt);
    body(K1s, V1s, qfh, oaH, lH, qrow_hi + lr, kt == qhi, kt);
    __syncthreads();
    ++kt;
    if (kt > qhi) break;
  }
  // epilogue: lane-domain l (every reg of lacc = l[q = lr]); oa reg dim = d.
  const float ilL = 1.0f / lL[0];
  const float ilH = 1.0f / lH[0];
  const size_t rowL = (size_t)b * T_DIM + qrow_lo + lr;
  const size_t rowH = (size_t)b * T_DIM + qrow_hi + lr;
#pragma unroll
  for (int dt = 0; dt < 4; ++dt) {
    bf16x4 wL, wH;
#pragma unroll
    for (int r = 0; r < 4; ++r) {
      wL[r] = (__bf16)(oaL[dt][r] * ilL);
      wH[r] = (__bf16)(oaH[dt][r] * ilH);
    }
    const int col = h * HD_DIM + dt * 16 + quad * 4;
    *(bf16x4*)&o[rowL * C_DIM + col] = wL;
    *(bf16x4*)&o[rowH * C_DIM + col] = wH;
  }
}

extern "C" void kernel_launch(void* const* d_in, const int* in_sizes, int n_in,
                              void* d_out, int out_size, void* d_ws, size_t ws_size,
                              hipStream_t stream) {
  const float* x    = (const float*)d_in[0];  // [B,T,C]
  const float* wqkv = (const float*)d_in[1];  // [3C,C]
  const float* wout = (const float*)d_in[2];  // [C,C]
  const float* cosp = (const float*)d_in[3];  // [1,1,512,8]
  const float* sinp = (const float*)d_in[4];  // [1,1,512,8]
  float* out = (float*)d_out;

  char* ws = (char*)d_ws;
  __bf16* xb    = (__bf16*)(ws);                    // 50331648 B
  __bf16* qb    = (__bf16*)(ws + 50331648);         // 50331648 B [M][384]
  __bf16* kb    = (__bf16*)(ws + 100663296);        // 50331648 B [M][384]
  __bf16* vtb   = (__bf16*)(ws + 150994944);        // 50331648 B [b*6+h][64][512]
  __bf16* ob    = (__bf16*)(ws + 201326592);        // 50331648 B [M][384]
  __bf16* wqkvb = (__bf16*)(ws + 251658240);        // 884736 B
  __bf16* woutb = (__bf16*)(ws + 252542976);        // 294912 B
  // total ws use: 252837888 bytes (identical to all prior clean runs)

  const int M = B_DIM * T_DIM;  // 65536

  // fused casts: 6291456 + 110592 + 36864 = 6438912 float4 units = 25152 blocks
  cast_all<<<25152, 256, 0, stream>>>(x, wqkv, wout, xb, wqkvb, woutb);

  // qkv = x @ Wqkv^T, epilogue splits: q (scaled+rope) / k (rope) / v^T -> vt
  gemm_bt<<<dim3(QKV_LD / 128, M / 128), 256, 0, stream>>>(
      xb, wqkvb, qb, kb, vtb, (float*)nullptr, cosp, sinp, M, QKV_LD, C_DIM);

  // causal flash attention -> o [65536][384] bf16 (1-D grid, T1 XCD swizzle)
  attn_kernel<<<3072, 256, 0, stream>>>(qb, kb, vtb, ob);

  // out = o @ Wout^T : fp32 (T1 swizzle, generic path, f32x4 stores)
  gemm_bt<<<dim3(C_DIM / 128, M / 128), 256, 0, stream>>>(
      ob, woutb, (__bf16*)nullptr, (__bf16*)nullptr, (__bf16*)nullptr, out,
      (const float*)nullptr, (const float*)nullptr, M, C_DIM, C_DIM);
}